// Round 14
// baseline (426.253 us; speedup 1.0000x reference)
//
#include <hip/hip_runtime.h>
#include <math.h>

#define BB 64
#define SS 1024
#define DD 32
#define HH 2
#define DHH 16
#define VV 28
#define QSC 0.3606737602222409f   // 0.25 * log2(e)
#define NCH 8                     // 8 chunks of 128 keys

typedef __attribute__((ext_vector_type(8))) short bf16x8;
typedef __attribute__((ext_vector_type(4))) float f32x4;

__device__ __forceinline__ unsigned pack_hi2(float a, float b) {
    return __builtin_amdgcn_perm(__float_as_uint(b), __float_as_uint(a), 0x07060302u);
}
__device__ __forceinline__ float trunc_hi(float a) {
    return __uint_as_float(__float_as_uint(a) & 0xFFFF0000u);
}
__device__ __forceinline__ bf16x8 as_bf16x8(uint4 u) {
    union { uint4 u; bf16x8 v; } cv; cv.u = u; return cv.v;
}

// Fragment-order layouts (validated R12). Consumer lane l reads byte l*16.
//  qf[bh][tile(64)][slot(64)][16B]                 : Q A-frags (quads 0,1 hi / 2,3 lo)
//  kf[bh][ch(8)][piece(g*8+t*2+plane)][slot][16B]  : K B-frags, hi/lo planes
//  vf[bh][ch(8)][piece(g*2+sub)][slot][16B]        : V B-frags (hi only)

// ---------------- kernel 1: MFMA QKV projection -> fragment order; e; W2; zero acc+cnt ------
__global__ __launch_bounds__(256) void k_pre(
        const int* __restrict__ x, const float* __restrict__ mask,
        const float* __restrict__ emb, const float* __restrict__ pe,
        const float* __restrict__ wq, const float* __restrict__ bq,
        const float* __restrict__ wk, const float* __restrict__ bk,
        const float* __restrict__ wv, const float* __restrict__ bv,
        const float* __restrict__ wo, const float* __restrict__ bo,
        const float* __restrict__ wfc, const float* __restrict__ bfc,
        int* __restrict__ e, float* __restrict__ W2, float* __restrict__ b2,
        char* __restrict__ qf, char* __restrict__ kf, char* __restrict__ vf,
        float* __restrict__ zacc) {
    int bid = blockIdx.x;
    int tid = threadIdx.x;
    if (bid < 1024) {
        __shared__ __align__(16) char hbuf[10240];
        __shared__ __align__(16) float Cb[4][16 * 17];
        char* hHi = hbuf;
        char* hLo = hbuf + 5120;
        int wave = tid >> 6, lane = tid & 63;
        int c = lane & 15, kq = lane >> 4;
        {
            int tt = tid >> 2, q4 = tid & 3;
            int idx = bid * 64 + tt;
            int b = idx >> 10, s = idx & 1023;
            float nm = (mask[b * SS + (s >= 3 ? s - 3 : 0)] != 0.0f) ? 1.0f : 0.0f;
            int tok = x[idx];
            float h[8];
#pragma unroll
            for (int i = 0; i < 8; i++)
                h[i] = (emb[tok * DD + q4 * 8 + i] + pe[s * DD + q4 * 8 + i]) * nm;
            unsigned wh[4], wl[4];
#pragma unroll
            for (int wd = 0; wd < 4; wd++) {
                float a0 = h[2 * wd], a1 = h[2 * wd + 1];
                wh[wd] = pack_hi2(a0, a1);
                wl[wd] = pack_hi2(a0 - trunc_hi(a0), a1 - trunc_hi(a1));
            }
            *(uint4*)(hHi + tt * 80 + q4 * 16) = uint4{wh[0], wh[1], wh[2], wh[3]};
            *(uint4*)(hLo + tt * 80 + q4 * 16) = uint4{wl[0], wl[1], wl[2], wl[3]};
        }
        __syncthreads();
        bf16x8 aHh, aHl;
        {
            int off = (wave * 16 + c) * 80 + kq * 16;
            aHh = *(const bf16x8*)(hHi + off);
            aHl = *(const bf16x8*)(hLo + off);
        }
        int blk_b = bid >> 4;
        int s_w = ((bid * 64) & 1023) + wave * 16;   // wave's 16 tokens start
        const f32x4 z4 = {0.0f, 0.0f, 0.0f, 0.0f};
#pragma unroll
        for (int M = 0; M < 3; M++) {
            const float* W    = M == 0 ? wq : (M == 1 ? wk : wv);
            const float* bias = M == 0 ? bq : (M == 1 ? bk : bv);
            bf16x8 Bh[2], Bl[2];
            float bv_[2];
#pragma unroll
            for (int nt = 0; nt < 2; nt++) {
                const float* wrow = W + (nt * 16 + c) * DD + kq * 8;
                float4 wa = ((const float4*)wrow)[0];
                float4 wb = ((const float4*)wrow)[1];
                float f[8] = {wa.x, wa.y, wa.z, wa.w, wb.x, wb.y, wb.z, wb.w};
                unsigned uh[4], ul[4];
#pragma unroll
                for (int wd = 0; wd < 4; wd++) {
                    float a0 = f[2 * wd], a1 = f[2 * wd + 1];
                    uh[wd] = pack_hi2(a0, a1);
                    ul[wd] = pack_hi2(a0 - trunc_hi(a0), a1 - trunc_hi(a1));
                }
                Bh[nt] = as_bf16x8(uint4{uh[0], uh[1], uh[2], uh[3]});
                Bl[nt] = as_bf16x8(uint4{ul[0], ul[1], ul[2], ul[3]});
                bv_[nt] = bias[nt * 16 + c];
            }
#pragma unroll
            for (int nt = 0; nt < 2; nt++) {
                f32x4 acc = __builtin_amdgcn_mfma_f32_16x16x32_bf16(aHh, Bh[nt], z4, 0, 0, 0);
                acc = __builtin_amdgcn_mfma_f32_16x16x32_bf16(aHl, Bh[nt], acc, 0, 0, 0);
                acc = __builtin_amdgcn_mfma_f32_16x16x32_bf16(aHh, Bl[nt], acc, 0, 0, 0);
#pragma unroll
                for (int r = 0; r < 4; r++) {
                    float val = acc[r] + bv_[nt];
                    if (M == 0) val *= QSC;
                    Cb[wave][(kq * 4 + r) * 17 + c] = val;
                }
                int bh = blk_b * 2 + nt;
                if (M == 0) {
                    int tile = s_w >> 4;
                    int qd = lane >> 4, cc = lane & 15;
                    float f[8];
#pragma unroll
                    for (int j = 0; j < 8; j++) f[j] = Cb[wave][cc * 17 + (qd & 1) * 8 + j];
                    unsigned u[4];
                    if (qd < 2) {
#pragma unroll
                        for (int wd = 0; wd < 4; wd++) u[wd] = pack_hi2(f[2 * wd], f[2 * wd + 1]);
                    } else {
#pragma unroll
                        for (int wd = 0; wd < 4; wd++) {
                            float a0 = f[2 * wd] - trunc_hi(f[2 * wd]);
                            float a1 = f[2 * wd + 1] - trunc_hi(f[2 * wd + 1]);
                            u[wd] = pack_hi2(a0, a1);
                        }
                    }
                    *(uint4*)(qf + ((size_t)((bh << 6) + tile) << 10) + lane * 16)
                        = uint4{u[0], u[1], u[2], u[3]};
                } else if (M == 1) {
                    int cl = lane & 3, qd = (lane >> 2) & 3, t = lane >> 4;
                    int ch = s_w >> 7, g = (s_w >> 6) & 1, c0 = (s_w & 63) >> 2;
                    int keyl = 4 * cl + t;
                    float f[8];
#pragma unroll
                    for (int j = 0; j < 8; j++) f[j] = Cb[wave][keyl * 17 + (qd & 1) * 8 + j];
                    unsigned uh[4], ul[4];
#pragma unroll
                    for (int wd = 0; wd < 4; wd++) {
                        float a0 = f[2 * wd], a1 = f[2 * wd + 1];
                        uh[wd] = pack_hi2(a0, a1);
                        ul[wd] = pack_hi2(a0 - trunc_hi(a0), a1 - trunc_hi(a1));
                    }
                    char* base = kf + ((size_t)((bh << 3) + ch) << 14)
                               + ((g << 3) + t * 2) * 1024 + qd * 256 + (c0 + cl) * 16;
                    *(uint4*)(base)        = uint4{uh[0], uh[1], uh[2], uh[3]};
                    *(uint4*)(base + 1024) = uint4{ul[0], ul[1], ul[2], ul[3]};
                } else if (lane < 32) {
                    int ch = s_w >> 7, g = (s_w >> 6) & 1, sub = (s_w >> 5) & 1;
                    int qs = (s_w & 31) >> 3;
                    int qrel = lane >> 4, dh = lane & 15;
                    unsigned u[4];
#pragma unroll
                    for (int wd = 0; wd < 4; wd++) {
                        float f0 = Cb[wave][(qrel * 8 + 2 * wd) * 17 + dh];
                        float f1 = Cb[wave][(qrel * 8 + 2 * wd + 1) * 17 + dh];
                        u[wd] = pack_hi2(f0, f1);
                    }
                    *(uint4*)(vf + ((size_t)((bh << 3) + ch) << 12)
                              + (g * 2 + sub) * 1024 + (qs + qrel) * 256 + dh * 16)
                        = uint4{u[0], u[1], u[2], u[3]};
                }
            }
        }
    } else if (bid < 1088) {
        int b = bid - 1024;
        int lm = -1;
        for (int s = tid; s < SS; s += 256)
            if (mask[b * SS + s] != 0.0f) lm = s;
        __shared__ int red[256];
        red[tid] = lm;
        __syncthreads();
        for (int off = 128; off > 0; off >>= 1) {
            if (tid < off) red[tid] = max(red[tid], red[tid + off]);
            __syncthreads();
        }
        if (tid == 0) {
            int last = red[0];
            int ee = last;
            if (last < SS - 1) ee = min(last + 3, SS - 1);
            e[b] = ee;
        }
    } else if (bid == 1088) {
        for (int t2 = tid; t2 < VV * DD + VV; t2 += 256) {
            if (t2 < VV * DD) {
                int vv = t2 / DD, i = t2 % DD;
                float a = 0.0f;
                for (int j = 0; j < DD; j++) a += wfc[vv * DD + j] * wo[j * DD + i];
                W2[t2] = a;
            } else {
                int vv = t2 - VV * DD;
                float a = bfc[vv];
                for (int j = 0; j < DD; j++) a += wfc[vv * DD + j] * bo[j];
                b2[vv] = a;
            }
        }
    } else {
        // zero oacc + lacc + cnt = 557568 float4 (contiguous)
        float4* z = (float4*)zacc;
        const float4 z4 = {0.0f, 0.0f, 0.0f, 0.0f};
        for (int i = (bid - 1089) * 256 + tid; i < 557568; i += 64 * 256) z[i] = z4;
    }
}

// ---------------- kernel 2: max-free MFMA attention + fused last-block FC epilogue ----------
// grid (32 qt, 64 b, 8 ch). Wave = 16 q x 1 head x <=128 keys, straight-line, atomics out.
// Per-(b,qt) counter: last of ceil(kmax/128) blocks normalizes + FCs its 32 tokens.
__global__ __launch_bounds__(256) void k_attn(
        const char* __restrict__ qf, const char* __restrict__ kf,
        const char* __restrict__ vf, const int* __restrict__ e,
        float* __restrict__ oacc, float* __restrict__ lacc, int* __restrict__ cnt,
        const float* __restrict__ W2, const float* __restrict__ b2,
        float* __restrict__ out) {
    __shared__ __align__(16) char Pb[18432];   // 4 waves x 2 g x (16 rows x 144B); epilogue aliases
    __shared__ int sflag;
    int tid = threadIdx.x;
    int qt = blockIdx.x, b = blockIdx.y, ch = blockIdx.z;
    int kmax = e[b] + 1;
    int k0 = ch * 128;
    if (k0 >= kmax) return;                    // dead chunks don't count toward the counter
    int ng = min(2, (kmax - k0 + 63) >> 6);

    int wave = tid >> 6, lane = tid & 63, quad = lane >> 4, c = lane & 15;
    int h = wave & 1;
    int tile = (qt << 1) + (wave >> 1);
    int qbase = tile << 4;
    int bh = b * 2 + h;

    char* Pw = Pb + wave * 4608;
    const char* kchunk = kf + ((size_t)((bh << 3) + ch) << 14);
    const char* vchunk = vf + ((size_t)((bh << 3) + ch) << 12);

    bf16x8 aQ = *(const bf16x8*)(qf + ((size_t)((bh << 6) + tile) << 10) + lane * 16);
    const f32x4 z4 = {0.0f, 0.0f, 0.0f, 0.0f};
    f32x4 accO = z4;
    float l_[4] = {0.0f, 0.0f, 0.0f, 0.0f};

#pragma unroll
    for (int g = 0; g < 2; g++) {
        if (g < ng) {
            bf16x8 bv0 = *(const bf16x8*)(vchunk + (g * 2 + 0) * 1024 + lane * 16);
            bf16x8 bv1 = *(const bf16x8*)(vchunk + (g * 2 + 1) * 1024 + lane * 16);
            const char* kg = kchunk + (g << 3) * 1024;
            f32x4 st[4];
#pragma unroll
            for (int t = 0; t < 4; t++) {
                bf16x8 bkh = *(const bf16x8*)(kg + (t * 2 + 0) * 1024 + lane * 16);
                bf16x8 bkl = *(const bf16x8*)(kg + (t * 2 + 1) * 1024 + lane * 16);
                f32x4 sv = __builtin_amdgcn_mfma_f32_16x16x32_bf16(aQ, bkl, z4, 0, 0, 0);
                sv = __builtin_amdgcn_mfma_f32_16x16x32_bf16(aQ, bkh, sv, 0, 0, 0);
                st[t] = sv;
            }
            if (k0 + g * 64 + 64 > kmax) {     // tail mask (rare)
#pragma unroll
                for (int t = 0; t < 4; t++) {
                    int key = k0 + g * 64 + 4 * c + t;
                    if (key >= kmax) st[t] = f32x4{-3e38f, -3e38f, -3e38f, -3e38f};
                }
            }
            float p[4][4];
#pragma unroll
            for (int t = 0; t < 4; t++)
#pragma unroll
                for (int r = 0; r < 4; r++) p[t][r] = exp2f(st[t][r]);
#pragma unroll
            for (int r = 0; r < 4; r++) {
                l_[r] += (p[0][r] + p[1][r]) + (p[2][r] + p[3][r]);
                unsigned lo = pack_hi2(p[0][r], p[1][r]);
                unsigned hi = pack_hi2(p[2][r], p[3][r]);
                *(uint2*)(Pw + g * 2304 + (quad * 4 + r) * 144 + c * 8) = uint2{lo, hi};
            }
            const char* Pra = Pw + g * 2304 + c * 144 + quad * 16;
            bf16x8 aP0 = *(const bf16x8*)(Pra);
            bf16x8 aP1 = *(const bf16x8*)(Pra + 64);
            accO = __builtin_amdgcn_mfma_f32_16x16x32_bf16(aP0, bv0, accO, 0, 0, 0);
            accO = __builtin_amdgcn_mfma_f32_16x16x32_bf16(aP1, bv1, accO, 0, 0, 0);
        }
    }

#pragma unroll
    for (int d = 1; d < 16; d <<= 1) {
#pragma unroll
        for (int r = 0; r < 4; r++) l_[r] += __shfl_xor(l_[r], d, 16);
    }
#pragma unroll
    for (int r = 0; r < 4; r++) {
        int q = qbase + quad * 4 + r;
        atomicAdd(oacc + ((size_t)((bh << 10) + q)) * 16 + c, accO[r]);
        if (c == 0) atomicAdd(lacc + (bh << 10) + q, l_[r]);
    }

    // ---- completion counter: last block for (b,qt) does normalize + FC ----
    __syncthreads();                           // drains vmcnt: all block atomics accepted
    if (tid == 0) {
        __threadfence();                       // release before the counter bump
        int old = atomicAdd(&cnt[b * 32 + qt], 1);
        int need = (kmax + 127) >> 7;          // live ch blocks for this b
        sflag = (old == need - 1) ? 1 : 0;
    }
    __syncthreads();
    if (sflag) {
        float* Obuf = (float*)Pb;              // 32 tokens x 32 floats
        float* Linv = (float*)(Pb + 4096);     // 32 tokens x 2 heads
        {
            int fi0 = tid * 4;                 // 4 consecutive floats per thread
            int tok = fi0 >> 5;
            int dim0 = fi0 & 31;
            int hh = dim0 >> 4;
            size_t row = (size_t)(((b * 2 + hh) << 10) + qt * 32 + tok);
            const float* src = oacc + row * 16 + (dim0 & 15);
#pragma unroll
            for (int i = 0; i < 4; i++)
                Obuf[fi0 + i] = __hip_atomic_load(src + i, __ATOMIC_RELAXED,
                                                  __HIP_MEMORY_SCOPE_AGENT);
        }
        if (tid < 64) {
            int tok = tid >> 1, hh = tid & 1;
            size_t row = (size_t)(((b * 2 + hh) << 10) + qt * 32 + tok);
            Linv[tok * 2 + hh] = 1.0f / __hip_atomic_load(lacc + row, __ATOMIC_RELAXED,
                                                          __HIP_MEMORY_SCOPE_AGENT);
        }
        __syncthreads();

        int tl = tid >> 3, j = tid & 7;
        float i0 = Linv[tl * 2 + 0], i1 = Linv[tl * 2 + 1];
        float ov[DD];
#pragma unroll
        for (int d = 0; d < 16; d++) {
            ov[d]      = Obuf[tl * 32 + d] * i0;
            ov[16 + d] = Obuf[tl * 32 + 16 + d] * i1;
        }
        size_t obase = (size_t)((b << 10) + qt * 32 + tl) * VV;
#pragma unroll
        for (int jj = 0; jj < 4; jj++) {
            int vv = j + jj * 8;
            if (vv < VV) {
                float a = b2[vv];
#pragma unroll
                for (int d = 0; d < DD; d += 4) {
                    const float* w4 = W2 + vv * DD + d;
                    a += ov[d] * w4[0] + ov[d + 1] * w4[1] + ov[d + 2] * w4[2] + ov[d + 3] * w4[3];
                }
                out[obase + vv] = a;
            }
        }
    }
}

extern "C" void kernel_launch(void* const* d_in, const int* in_sizes, int n_in,
                              void* d_out, int out_size, void* d_ws, size_t ws_size,
                              hipStream_t stream) {
    const int*   x    = (const int*)d_in[0];
    const float* mask = (const float*)d_in[1];
    const float* emb  = (const float*)d_in[2];
    const float* pe   = (const float*)d_in[3];
    const float* wq   = (const float*)d_in[4];
    const float* bq   = (const float*)d_in[5];
    const float* wk   = (const float*)d_in[6];
    const float* bk   = (const float*)d_in[7];
    const float* wv   = (const float*)d_in[8];
    const float* bv   = (const float*)d_in[9];
    const float* wo   = (const float*)d_in[10];
    const float* bo   = (const float*)d_in[11];
    const float* wfc  = (const float*)d_in[12];
    const float* bfc  = (const float*)d_in[13];
    float* out = (float*)d_out;

    char* ws = (char*)d_ws;
    int*   e  = (int*)ws;                                     // 256 B
    float* W2 = (float*)(ws + 256);
    float* b2 = (float*)(ws + 3840);
    char*  qf = ws + 4096;                                    // 8 MiB  [bh][tile][slot]
    char*  kf = qf + (size_t)8388608;                         // 16 MiB [bh][ch][piece][slot]
    char*  vf = kf + (size_t)16777216;                        // 4 MiB  [bh][ch][piece][slot]
    float* oacc = (float*)(vf + (size_t)4194304);             // 8 MiB
    float* lacc = oacc + (size_t)BB * HH * SS * 16;           // 0.5 MiB
    int*   cnt  = (int*)(lacc + (size_t)BB * HH * SS);        // 8 KiB (64 b x 32 qt)

    hipLaunchKernelGGL(k_pre, dim3(1153), dim3(256), 0, stream,
                       x, mask, emb, pe, wq, bq, wk, bk, wv, bv, wo, bo, wfc, bfc,
                       e, W2, b2, qf, kf, vf, oacc);
    hipLaunchKernelGGL(k_attn, dim3(SS / 32, BB, NCH), dim3(256), 0, stream,
                       qf, kf, vf, e, oacc, lacc, cnt, W2, b2, out);
}

// Round 15
// 145.184 us; speedup vs baseline: 2.9360x; 2.9360x over previous
//
#include <hip/hip_runtime.h>
#include <math.h>

#define BB 64
#define SS 1024
#define DD 32
#define HH 2
#define DHH 16
#define VV 28
#define QSC 0.3606737602222409f   // 0.25 * log2(e)
#define NCH 4                     // 4 chunks of 256 keys

typedef __attribute__((ext_vector_type(8))) short bf16x8;
typedef __attribute__((ext_vector_type(4))) float f32x4;

__device__ __forceinline__ unsigned pack_hi2(float a, float b) {
    return __builtin_amdgcn_perm(__float_as_uint(b), __float_as_uint(a), 0x07060302u);
}
__device__ __forceinline__ float trunc_hi(float a) {
    return __uint_as_float(__float_as_uint(a) & 0xFFFF0000u);
}
__device__ __forceinline__ bf16x8 as_bf16x8(uint4 u) {
    union { uint4 u; bf16x8 v; } cv; cv.u = u; return cv.v;
}

// Fragment-order layouts (validated R12). Consumer lane l reads byte l*16.
//  qf[bh][tile(64)][slot(64)][16B]                   : Q A-frags (quads 0,1 hi / 2,3 lo)
//  kf[bh][kch8(8)][piece(g*8+t*2+plane)][slot][16B]  : K B-frags, hi/lo planes (128-key groups of 8)
//  vf[bh][kch8(8)][piece(g*2+sub)][slot][16B]        : V B-frags (hi only)
// k_attn uses 256-key chunks = 2 consecutive kch8 groups.

// ---------------- kernel 1: MFMA QKV projection -> fragment order; e; W2; zero acc ----------
__global__ __launch_bounds__(256) void k_pre(
        const int* __restrict__ x, const float* __restrict__ mask,
        const float* __restrict__ emb, const float* __restrict__ pe,
        const float* __restrict__ wq, const float* __restrict__ bq,
        const float* __restrict__ wk, const float* __restrict__ bk,
        const float* __restrict__ wv, const float* __restrict__ bv,
        const float* __restrict__ wo, const float* __restrict__ bo,
        const float* __restrict__ wfc, const float* __restrict__ bfc,
        int* __restrict__ e, float* __restrict__ W2, float* __restrict__ b2,
        char* __restrict__ qf, char* __restrict__ kf, char* __restrict__ vf,
        float* __restrict__ zacc) {
    int bid = blockIdx.x;
    int tid = threadIdx.x;
    if (bid < 1024) {
        __shared__ __align__(16) char hbuf[10240];
        __shared__ __align__(16) float Cb[4][16 * 17];
        char* hHi = hbuf;
        char* hLo = hbuf + 5120;
        int wave = tid >> 6, lane = tid & 63;
        int c = lane & 15, kq = lane >> 4;
        {
            int tt = tid >> 2, q4 = tid & 3;
            int idx = bid * 64 + tt;
            int b = idx >> 10, s = idx & 1023;
            float nm = (mask[b * SS + (s >= 3 ? s - 3 : 0)] != 0.0f) ? 1.0f : 0.0f;
            int tok = x[idx];
            float h[8];
#pragma unroll
            for (int i = 0; i < 8; i++)
                h[i] = (emb[tok * DD + q4 * 8 + i] + pe[s * DD + q4 * 8 + i]) * nm;
            unsigned wh[4], wl[4];
#pragma unroll
            for (int wd = 0; wd < 4; wd++) {
                float a0 = h[2 * wd], a1 = h[2 * wd + 1];
                wh[wd] = pack_hi2(a0, a1);
                wl[wd] = pack_hi2(a0 - trunc_hi(a0), a1 - trunc_hi(a1));
            }
            *(uint4*)(hHi + tt * 80 + q4 * 16) = uint4{wh[0], wh[1], wh[2], wh[3]};
            *(uint4*)(hLo + tt * 80 + q4 * 16) = uint4{wl[0], wl[1], wl[2], wl[3]};
        }
        __syncthreads();
        bf16x8 aHh, aHl;
        {
            int off = (wave * 16 + c) * 80 + kq * 16;
            aHh = *(const bf16x8*)(hHi + off);
            aHl = *(const bf16x8*)(hLo + off);
        }
        int blk_b = bid >> 4;
        int s_w = ((bid * 64) & 1023) + wave * 16;   // wave's 16 tokens start
        const f32x4 z4 = {0.0f, 0.0f, 0.0f, 0.0f};
#pragma unroll
        for (int M = 0; M < 3; M++) {
            const float* W    = M == 0 ? wq : (M == 1 ? wk : wv);
            const float* bias = M == 0 ? bq : (M == 1 ? bk : bv);
            bf16x8 Bh[2], Bl[2];
            float bv_[2];
#pragma unroll
            for (int nt = 0; nt < 2; nt++) {
                const float* wrow = W + (nt * 16 + c) * DD + kq * 8;
                float4 wa = ((const float4*)wrow)[0];
                float4 wb = ((const float4*)wrow)[1];
                float f[8] = {wa.x, wa.y, wa.z, wa.w, wb.x, wb.y, wb.z, wb.w};
                unsigned uh[4], ul[4];
#pragma unroll
                for (int wd = 0; wd < 4; wd++) {
                    float a0 = f[2 * wd], a1 = f[2 * wd + 1];
                    uh[wd] = pack_hi2(a0, a1);
                    ul[wd] = pack_hi2(a0 - trunc_hi(a0), a1 - trunc_hi(a1));
                }
                Bh[nt] = as_bf16x8(uint4{uh[0], uh[1], uh[2], uh[3]});
                Bl[nt] = as_bf16x8(uint4{ul[0], ul[1], ul[2], ul[3]});
                bv_[nt] = bias[nt * 16 + c];
            }
#pragma unroll
            for (int nt = 0; nt < 2; nt++) {
                f32x4 acc = __builtin_amdgcn_mfma_f32_16x16x32_bf16(aHh, Bh[nt], z4, 0, 0, 0);
                acc = __builtin_amdgcn_mfma_f32_16x16x32_bf16(aHl, Bh[nt], acc, 0, 0, 0);
                acc = __builtin_amdgcn_mfma_f32_16x16x32_bf16(aHh, Bl[nt], acc, 0, 0, 0);
#pragma unroll
                for (int r = 0; r < 4; r++) {
                    float val = acc[r] + bv_[nt];
                    if (M == 0) val *= QSC;
                    Cb[wave][(kq * 4 + r) * 17 + c] = val;
                }
                int bh = blk_b * 2 + nt;
                if (M == 0) {
                    int tile = s_w >> 4;
                    int qd = lane >> 4, cc = lane & 15;
                    float f[8];
#pragma unroll
                    for (int j = 0; j < 8; j++) f[j] = Cb[wave][cc * 17 + (qd & 1) * 8 + j];
                    unsigned u[4];
                    if (qd < 2) {
#pragma unroll
                        for (int wd = 0; wd < 4; wd++) u[wd] = pack_hi2(f[2 * wd], f[2 * wd + 1]);
                    } else {
#pragma unroll
                        for (int wd = 0; wd < 4; wd++) {
                            float a0 = f[2 * wd] - trunc_hi(f[2 * wd]);
                            float a1 = f[2 * wd + 1] - trunc_hi(f[2 * wd + 1]);
                            u[wd] = pack_hi2(a0, a1);
                        }
                    }
                    *(uint4*)(qf + ((size_t)((bh << 6) + tile) << 10) + lane * 16)
                        = uint4{u[0], u[1], u[2], u[3]};
                } else if (M == 1) {
                    int cl = lane & 3, qd = (lane >> 2) & 3, t = lane >> 4;
                    int ch = s_w >> 7, g = (s_w >> 6) & 1, c0 = (s_w & 63) >> 2;
                    int keyl = 4 * cl + t;
                    float f[8];
#pragma unroll
                    for (int j = 0; j < 8; j++) f[j] = Cb[wave][keyl * 17 + (qd & 1) * 8 + j];
                    unsigned uh[4], ul[4];
#pragma unroll
                    for (int wd = 0; wd < 4; wd++) {
                        float a0 = f[2 * wd], a1 = f[2 * wd + 1];
                        uh[wd] = pack_hi2(a0, a1);
                        ul[wd] = pack_hi2(a0 - trunc_hi(a0), a1 - trunc_hi(a1));
                    }
                    char* base = kf + ((size_t)((bh << 3) + ch) << 14)
                               + ((g << 3) + t * 2) * 1024 + qd * 256 + (c0 + cl) * 16;
                    *(uint4*)(base)        = uint4{uh[0], uh[1], uh[2], uh[3]};
                    *(uint4*)(base + 1024) = uint4{ul[0], ul[1], ul[2], ul[3]};
                } else if (lane < 32) {
                    int ch = s_w >> 7, g = (s_w >> 6) & 1, sub = (s_w >> 5) & 1;
                    int qs = (s_w & 31) >> 3;
                    int qrel = lane >> 4, dh = lane & 15;
                    unsigned u[4];
#pragma unroll
                    for (int wd = 0; wd < 4; wd++) {
                        float f0 = Cb[wave][(qrel * 8 + 2 * wd) * 17 + dh];
                        float f1 = Cb[wave][(qrel * 8 + 2 * wd + 1) * 17 + dh];
                        u[wd] = pack_hi2(f0, f1);
                    }
                    *(uint4*)(vf + ((size_t)((bh << 3) + ch) << 12)
                              + (g * 2 + sub) * 1024 + (qs + qrel) * 256 + dh * 16)
                        = uint4{u[0], u[1], u[2], u[3]};
                }
            }
        }
    } else if (bid < 1088) {
        int b = bid - 1024;
        int lm = -1;
        for (int s = tid; s < SS; s += 256)
            if (mask[b * SS + s] != 0.0f) lm = s;
        __shared__ int red[256];
        red[tid] = lm;
        __syncthreads();
        for (int off = 128; off > 0; off >>= 1) {
            if (tid < off) red[tid] = max(red[tid], red[tid + off]);
            __syncthreads();
        }
        if (tid == 0) {
            int last = red[0];
            int ee = last;
            if (last < SS - 1) ee = min(last + 3, SS - 1);
            e[b] = ee;
        }
    } else if (bid == 1088) {
        for (int t2 = tid; t2 < VV * DD + VV; t2 += 256) {
            if (t2 < VV * DD) {
                int vv = t2 / DD, i = t2 % DD;
                float a = 0.0f;
                for (int j = 0; j < DD; j++) a += wfc[vv * DD + j] * wo[j * DD + i];
                W2[t2] = a;
            } else {
                int vv = t2 - VV * DD;
                float a = bfc[vv];
                for (int j = 0; j < DD; j++) a += wfc[vv * DD + j] * bo[j];
                b2[vv] = a;
            }
        }
    } else {
        // zero oacc + lacc = 557056 float4 (contiguous)
        float4* z = (float4*)zacc;
        const float4 z4 = {0.0f, 0.0f, 0.0f, 0.0f};
        for (int i = (bid - 1089) * 256 + tid; i < 557056; i += 64 * 256) z[i] = z4;
    }
}

// ---------------- kernel 2: max-free MFMA attention, 256-key chunks ----------------
// grid (32 qt, 64 b, 4 ch). Wave = 16 q x 1 head x <=256 keys (4 groups of 64), straight-line.
// P-buffer alternates g&1 (per-wave, ordered by lgkmcnt; no barrier).
__global__ __launch_bounds__(256) void k_attn(
        const char* __restrict__ qf, const char* __restrict__ kf,
        const char* __restrict__ vf, const int* __restrict__ e,
        float* __restrict__ oacc, float* __restrict__ lacc) {
    __shared__ __align__(16) char Pb[18432];   // 4 waves x 2 bufs x (16 rows x 144B)
    int tid = threadIdx.x;
    int qt = blockIdx.x, b = blockIdx.y, ch = blockIdx.z;
    int kmax = e[b] + 1;
    int k0 = ch << 8;
    if (k0 >= kmax) return;
    int ng = min(4, (kmax - k0 + 63) >> 6);    // 1..4 live 64-key groups

    int wave = tid >> 6, lane = tid & 63, quad = lane >> 4, c = lane & 15;
    int h = wave & 1;
    int tile = (qt << 1) + (wave >> 1);
    int qbase = tile << 4;
    int bh = b * 2 + h;

    char* Pw = Pb + wave * 4608;
    // 256-key chunk spans kch8 groups 2*ch and 2*ch+1
    const char* kchunk = kf + ((size_t)((bh << 3) + (ch << 1)) << 14);
    const char* vchunk = vf + ((size_t)((bh << 3) + (ch << 1)) << 12);

    bf16x8 aQ = *(const bf16x8*)(qf + ((size_t)((bh << 6) + tile) << 10) + lane * 16);
    const f32x4 z4 = {0.0f, 0.0f, 0.0f, 0.0f};
    f32x4 accO = z4;
    float l_[4] = {0.0f, 0.0f, 0.0f, 0.0f};

#pragma unroll
    for (int g = 0; g < 4; g++) {
        if (g < ng) {
            // g in [0,4): kch8 index = g>>1, inner group = g&1
            const char* kg = kchunk + (size_t)(g >> 1) * 16384 + (size_t)(g & 1) * 8192;
            const char* vg = vchunk + (size_t)(g >> 1) * 4096 + (size_t)(g & 1) * 2048;
            bf16x8 bv0 = *(const bf16x8*)(vg + lane * 16);
            bf16x8 bv1 = *(const bf16x8*)(vg + 1024 + lane * 16);
            f32x4 st[4];
#pragma unroll
            for (int t = 0; t < 4; t++) {
                bf16x8 bkh = *(const bf16x8*)(kg + (t * 2 + 0) * 1024 + lane * 16);
                bf16x8 bkl = *(const bf16x8*)(kg + (t * 2 + 1) * 1024 + lane * 16);
                f32x4 sv = __builtin_amdgcn_mfma_f32_16x16x32_bf16(aQ, bkl, z4, 0, 0, 0);
                sv = __builtin_amdgcn_mfma_f32_16x16x32_bf16(aQ, bkh, sv, 0, 0, 0);
                st[t] = sv;
            }
            if (k0 + g * 64 + 64 > kmax) {     // tail mask (last live group only)
#pragma unroll
                for (int t = 0; t < 4; t++) {
                    int key = k0 + g * 64 + 4 * c + t;
                    if (key >= kmax) st[t] = f32x4{-3e38f, -3e38f, -3e38f, -3e38f};
                }
            }
            float p[4][4];
#pragma unroll
            for (int t = 0; t < 4; t++)
#pragma unroll
                for (int r = 0; r < 4; r++) p[t][r] = exp2f(st[t][r]);
            char* Pg = Pw + (g & 1) * 2304;
#pragma unroll
            for (int r = 0; r < 4; r++) {
                l_[r] += (p[0][r] + p[1][r]) + (p[2][r] + p[3][r]);
                unsigned lo = pack_hi2(p[0][r], p[1][r]);
                unsigned hi = pack_hi2(p[2][r], p[3][r]);
                *(uint2*)(Pg + (quad * 4 + r) * 144 + c * 8) = uint2{lo, hi};
            }
            const char* Pra = Pg + c * 144 + quad * 16;
            bf16x8 aP0 = *(const bf16x8*)(Pra);
            bf16x8 aP1 = *(const bf16x8*)(Pra + 64);
            accO = __builtin_amdgcn_mfma_f32_16x16x32_bf16(aP0, bv0, accO, 0, 0, 0);
            accO = __builtin_amdgcn_mfma_f32_16x16x32_bf16(aP1, bv1, accO, 0, 0, 0);
        }
    }

#pragma unroll
    for (int d = 1; d < 16; d <<= 1) {
#pragma unroll
        for (int r = 0; r < 4; r++) l_[r] += __shfl_xor(l_[r], d, 16);
    }
#pragma unroll
    for (int r = 0; r < 4; r++) {
        int q = qbase + quad * 4 + r;
        atomicAdd(oacc + ((size_t)((bh << 10) + q)) * 16 + c, accO[r]);
        if (c == 0) atomicAdd(lacc + (bh << 10) + q, l_[r]);
    }
}

// ---------------- kernel 3: normalize + out = O @ W2^T + b2 ----------------
__global__ __launch_bounds__(256) void k_fc(
        const float* __restrict__ oacc, const float* __restrict__ lacc,
        const float* __restrict__ W2, const float* __restrict__ b2,
        float* __restrict__ out) {
    __shared__ float Ob[128 * 36];
    __shared__ float sW[VV * 36];
    __shared__ float sb[VV];
    int tid = threadIdx.x;
    for (int i = tid; i < VV * DD; i += 256) sW[(i >> 5) * 36 + (i & 31)] = W2[i];
    if (tid < VV) sb[tid] = b2[tid];

    int tl = tid >> 1, hh = tid & 1;
    int idx = blockIdx.x * 128 + tl;
    int b = idx >> 10, s = idx & 1023;
    size_t row = (size_t)((b * 2 + hh) << 10) + s;

    float inv = 1.0f / lacc[row];
    const float4* pr = (const float4*)(oacc + row * 16);
    float4 o0 = pr[0], o1 = pr[1], o2 = pr[2], o3 = pr[3];
    float* obr = Ob + tl * 36 + hh * DHH;
    obr[0]  = o0.x * inv; obr[1]  = o0.y * inv; obr[2]  = o0.z * inv; obr[3]  = o0.w * inv;
    obr[4]  = o1.x * inv; obr[5]  = o1.y * inv; obr[6]  = o1.z * inv; obr[7]  = o1.w * inv;
    obr[8]  = o2.x * inv; obr[9]  = o2.y * inv; obr[10] = o2.z * inv; obr[11] = o2.w * inv;
    obr[12] = o3.x * inv; obr[13] = o3.y * inv; obr[14] = o3.z * inv; obr[15] = o3.w * inv;
    __syncthreads();

    const float* orow = Ob + tl * 36;
    float ov[DD];
#pragma unroll
    for (int i = 0; i < DD; i += 4) {
        float4 t4 = *(const float4*)(orow + i);
        ov[i] = t4.x; ov[i + 1] = t4.y; ov[i + 2] = t4.z; ov[i + 3] = t4.w;
    }
    size_t obase = (size_t)idx * VV + hh * 14;
#pragma unroll
    for (int jj = 0; jj < 14; jj++) {
        int vv = hh * 14 + jj;
        float a = sb[vv];
#pragma unroll
        for (int d = 0; d < DD; d += 4) {
            float4 w4 = *(const float4*)(sW + vv * 36 + d);
            a += ov[d] * w4.x + ov[d + 1] * w4.y + ov[d + 2] * w4.z + ov[d + 3] * w4.w;
        }
        out[obase + jj] = a;
    }
}

extern "C" void kernel_launch(void* const* d_in, const int* in_sizes, int n_in,
                              void* d_out, int out_size, void* d_ws, size_t ws_size,
                              hipStream_t stream) {
    const int*   x    = (const int*)d_in[0];
    const float* mask = (const float*)d_in[1];
    const float* emb  = (const float*)d_in[2];
    const float* pe   = (const float*)d_in[3];
    const float* wq   = (const float*)d_in[4];
    const float* bq   = (const float*)d_in[5];
    const float* wk   = (const float*)d_in[6];
    const float* bk   = (const float*)d_in[7];
    const float* wv   = (const float*)d_in[8];
    const float* bv   = (const float*)d_in[9];
    const float* wo   = (const float*)d_in[10];
    const float* bo   = (const float*)d_in[11];
    const float* wfc  = (const float*)d_in[12];
    const float* bfc  = (const float*)d_in[13];
    float* out = (float*)d_out;

    char* ws = (char*)d_ws;
    int*   e  = (int*)ws;                                     // 256 B
    float* W2 = (float*)(ws + 256);
    float* b2 = (float*)(ws + 3840);
    char*  qf = ws + 4096;                                    // 8 MiB  [bh][tile][slot]
    char*  kf = qf + (size_t)8388608;                         // 16 MiB [bh][kch8][piece][slot]
    char*  vf = kf + (size_t)16777216;                        // 4 MiB  [bh][kch8][piece][slot]
    float* oacc = (float*)(vf + (size_t)4194304);             // 8 MiB
    float* lacc = oacc + (size_t)BB * HH * SS * 16;           // 0.5 MiB

    hipLaunchKernelGGL(k_pre, dim3(1153), dim3(256), 0, stream,
                       x, mask, emb, pe, wq, bq, wk, bk, wv, bv, wo, bo, wfc, bfc,
                       e, W2, b2, qf, kf, vf, oacc);
    hipLaunchKernelGGL(k_attn, dim3(SS / 32, BB, NCH), dim3(256), 0, stream,
                       qf, kf, vf, e, oacc, lacc);
    hipLaunchKernelGGL(k_fc, dim3(BB * SS / 128), dim3(256), 0, stream,
                       oacc, lacc, W2, b2, out);
}

// Round 16
// 138.419 us; speedup vs baseline: 3.0794x; 1.0489x over previous
//
#include <hip/hip_runtime.h>
#include <math.h>

#define BB 64
#define SS 1024
#define DD 32
#define HH 2
#define DHH 16
#define VV 28
#define QSC 0.3606737602222409f   // 0.25 * log2(e)
#define NCH 4                     // 4 chunks of 256 keys

typedef __attribute__((ext_vector_type(8))) short bf16x8;
typedef __attribute__((ext_vector_type(4))) float f32x4;

__device__ __forceinline__ unsigned pack_hi2(float a, float b) {
    return __builtin_amdgcn_perm(__float_as_uint(b), __float_as_uint(a), 0x07060302u);
}
__device__ __forceinline__ float trunc_hi(float a) {
    return __uint_as_float(__float_as_uint(a) & 0xFFFF0000u);
}
__device__ __forceinline__ unsigned bf_rtne_u(float x) {
    unsigned u = __float_as_uint(x);
    return (u + 0x7FFFu + ((u >> 16) & 1u)) >> 16;
}
__device__ __forceinline__ unsigned pack_rtne2(float a, float b) {
    return bf_rtne_u(a) | (bf_rtne_u(b) << 16);
}
__device__ __forceinline__ bf16x8 as_bf16x8(uint4 u) {
    union { uint4 u; bf16x8 v; } cv; cv.u = u; return cv.v;
}

// Fragment-order layouts. Consumer lane l reads byte l*16.
//  qf[bh][tile(64)][slot(64)][16B]                 : Q A-frags (quads 0,1 hi / 2,3 lo) — exact hi/lo split
//  kf[bh][kch8(8)][piece(g*4+t)][slot][16B]        : K B-frags, RTNE bf16, [kh;kh] duplication baked in
//  vf[bh][kch8(8)][piece(g*2+sub)][slot][16B]      : V B-frags, RTNE bf16
// k_attn uses 256-key chunks = 2 consecutive kch8 groups; group g's pieces are contiguous.

// ---------------- kernel 1: MFMA QKV projection -> fragment order; e; W2; zero acc ----------
__global__ __launch_bounds__(256) void k_pre(
        const int* __restrict__ x, const float* __restrict__ mask,
        const float* __restrict__ emb, const float* __restrict__ pe,
        const float* __restrict__ wq, const float* __restrict__ bq,
        const float* __restrict__ wk, const float* __restrict__ bk,
        const float* __restrict__ wv, const float* __restrict__ bv,
        const float* __restrict__ wo, const float* __restrict__ bo,
        const float* __restrict__ wfc, const float* __restrict__ bfc,
        int* __restrict__ e, float* __restrict__ W2, float* __restrict__ b2,
        char* __restrict__ qf, char* __restrict__ kf, char* __restrict__ vf,
        float* __restrict__ zacc) {
    int bid = blockIdx.x;
    int tid = threadIdx.x;
    if (bid < 1024) {
        __shared__ __align__(16) char hbuf[10240];
        __shared__ __align__(16) float Cb[4][16 * 17];
        char* hHi = hbuf;
        char* hLo = hbuf + 5120;
        int wave = tid >> 6, lane = tid & 63;
        int c = lane & 15, kq = lane >> 4;
        {
            int tt = tid >> 2, q4 = tid & 3;
            int idx = bid * 64 + tt;
            int b = idx >> 10, s = idx & 1023;
            float nm = (mask[b * SS + (s >= 3 ? s - 3 : 0)] != 0.0f) ? 1.0f : 0.0f;
            int tok = x[idx];
            float h[8];
#pragma unroll
            for (int i = 0; i < 8; i++)
                h[i] = (emb[tok * DD + q4 * 8 + i] + pe[s * DD + q4 * 8 + i]) * nm;
            unsigned wh[4], wl[4];
#pragma unroll
            for (int wd = 0; wd < 4; wd++) {
                float a0 = h[2 * wd], a1 = h[2 * wd + 1];
                wh[wd] = pack_hi2(a0, a1);
                wl[wd] = pack_hi2(a0 - trunc_hi(a0), a1 - trunc_hi(a1));
            }
            *(uint4*)(hHi + tt * 80 + q4 * 16) = uint4{wh[0], wh[1], wh[2], wh[3]};
            *(uint4*)(hLo + tt * 80 + q4 * 16) = uint4{wl[0], wl[1], wl[2], wl[3]};
        }
        __syncthreads();
        bf16x8 aHh, aHl;
        {
            int off = (wave * 16 + c) * 80 + kq * 16;
            aHh = *(const bf16x8*)(hHi + off);
            aHl = *(const bf16x8*)(hLo + off);
        }
        int blk_b = bid >> 4;
        int s_w = ((bid * 64) & 1023) + wave * 16;   // wave's 16 tokens start
        const f32x4 z4 = {0.0f, 0.0f, 0.0f, 0.0f};
#pragma unroll
        for (int M = 0; M < 3; M++) {
            const float* W    = M == 0 ? wq : (M == 1 ? wk : wv);
            const float* bias = M == 0 ? bq : (M == 1 ? bk : bv);
            bf16x8 Bh[2], Bl[2];
            float bv_[2];
#pragma unroll
            for (int nt = 0; nt < 2; nt++) {
                const float* wrow = W + (nt * 16 + c) * DD + kq * 8;
                float4 wa = ((const float4*)wrow)[0];
                float4 wb = ((const float4*)wrow)[1];
                float f[8] = {wa.x, wa.y, wa.z, wa.w, wb.x, wb.y, wb.z, wb.w};
                unsigned uh[4], ul[4];
#pragma unroll
                for (int wd = 0; wd < 4; wd++) {
                    float a0 = f[2 * wd], a1 = f[2 * wd + 1];
                    uh[wd] = pack_hi2(a0, a1);
                    ul[wd] = pack_hi2(a0 - trunc_hi(a0), a1 - trunc_hi(a1));
                }
                Bh[nt] = as_bf16x8(uint4{uh[0], uh[1], uh[2], uh[3]});
                Bl[nt] = as_bf16x8(uint4{ul[0], ul[1], ul[2], ul[3]});
                bv_[nt] = bias[nt * 16 + c];
            }
#pragma unroll
            for (int nt = 0; nt < 2; nt++) {
                f32x4 acc = __builtin_amdgcn_mfma_f32_16x16x32_bf16(aHh, Bh[nt], z4, 0, 0, 0);
                acc = __builtin_amdgcn_mfma_f32_16x16x32_bf16(aHl, Bh[nt], acc, 0, 0, 0);
                acc = __builtin_amdgcn_mfma_f32_16x16x32_bf16(aHh, Bl[nt], acc, 0, 0, 0);
#pragma unroll
                for (int r = 0; r < 4; r++) {
                    float val = acc[r] + bv_[nt];
                    if (M == 0) val *= QSC;
                    Cb[wave][(kq * 4 + r) * 17 + c] = val;
                }
                int bh = blk_b * 2 + nt;
                if (M == 0) {
                    // Q: exact hi/lo split (quads 0,1 hi; 2,3 lo), truncation split (exact sum)
                    int tile = s_w >> 4;
                    int qd = lane >> 4, cc = lane & 15;
                    float f[8];
#pragma unroll
                    for (int j = 0; j < 8; j++) f[j] = Cb[wave][cc * 17 + (qd & 1) * 8 + j];
                    unsigned u[4];
                    if (qd < 2) {
#pragma unroll
                        for (int wd = 0; wd < 4; wd++) u[wd] = pack_hi2(f[2 * wd], f[2 * wd + 1]);
                    } else {
#pragma unroll
                        for (int wd = 0; wd < 4; wd++) {
                            float a0 = f[2 * wd] - trunc_hi(f[2 * wd]);
                            float a1 = f[2 * wd + 1] - trunc_hi(f[2 * wd + 1]);
                            u[wd] = pack_hi2(a0, a1);
                        }
                    }
                    *(uint4*)(qf + ((size_t)((bh << 6) + tile) << 10) + lane * 16)
                        = uint4{u[0], u[1], u[2], u[3]};
                } else if (M == 1) {
                    // K: single RTNE plane, [kh;kh] duplication via qd 0-3
                    int cl = lane & 3, qd = (lane >> 2) & 3, t = lane >> 4;
                    int ch = s_w >> 7, g = (s_w >> 6) & 1, c0 = (s_w & 63) >> 2;
                    int keyl = 4 * cl + t;
                    float f[8];
#pragma unroll
                    for (int j = 0; j < 8; j++) f[j] = Cb[wave][keyl * 17 + (qd & 1) * 8 + j];
                    unsigned uh[4];
#pragma unroll
                    for (int wd = 0; wd < 4; wd++) uh[wd] = pack_rtne2(f[2 * wd], f[2 * wd + 1]);
                    char* base = kf + ((size_t)((bh << 3) + ch) << 13)
                               + ((g << 2) + t) * 1024 + qd * 256 + (c0 + cl) * 16;
                    *(uint4*)(base) = uint4{uh[0], uh[1], uh[2], uh[3]};
                } else if (lane < 32) {
                    // V: RTNE bf16
                    int ch = s_w >> 7, g = (s_w >> 6) & 1, sub = (s_w >> 5) & 1;
                    int qs = (s_w & 31) >> 3;
                    int qrel = lane >> 4, dh = lane & 15;
                    unsigned u[4];
#pragma unroll
                    for (int wd = 0; wd < 4; wd++) {
                        float f0 = Cb[wave][(qrel * 8 + 2 * wd) * 17 + dh];
                        float f1 = Cb[wave][(qrel * 8 + 2 * wd + 1) * 17 + dh];
                        u[wd] = pack_rtne2(f0, f1);
                    }
                    *(uint4*)(vf + ((size_t)((bh << 3) + ch) << 12)
                              + (g * 2 + sub) * 1024 + (qs + qrel) * 256 + dh * 16)
                        = uint4{u[0], u[1], u[2], u[3]};
                }
            }
        }
    } else if (bid < 1088) {
        int b = bid - 1024;
        int lm = -1;
        for (int s = tid; s < SS; s += 256)
            if (mask[b * SS + s] != 0.0f) lm = s;
        __shared__ int red[256];
        red[tid] = lm;
        __syncthreads();
        for (int off = 128; off > 0; off >>= 1) {
            if (tid < off) red[tid] = max(red[tid], red[tid + off]);
            __syncthreads();
        }
        if (tid == 0) {
            int last = red[0];
            int ee = last;
            if (last < SS - 1) ee = min(last + 3, SS - 1);
            e[b] = ee;
        }
    } else if (bid == 1088) {
        for (int t2 = tid; t2 < VV * DD + VV; t2 += 256) {
            if (t2 < VV * DD) {
                int vv = t2 / DD, i = t2 % DD;
                float a = 0.0f;
                for (int j = 0; j < DD; j++) a += wfc[vv * DD + j] * wo[j * DD + i];
                W2[t2] = a;
            } else {
                int vv = t2 - VV * DD;
                float a = bfc[vv];
                for (int j = 0; j < DD; j++) a += wfc[vv * DD + j] * bo[j];
                b2[vv] = a;
            }
        }
    } else {
        // zero oacc + lacc = 557056 float4 (contiguous)
        float4* z = (float4*)zacc;
        const float4 z4 = {0.0f, 0.0f, 0.0f, 0.0f};
        for (int i = (bid - 1089) * 256 + tid; i < 557056; i += 64 * 256) z[i] = z4;
    }
}

// ---------------- kernel 2: max-free MFMA attention, 256-key chunks, single-plane K ---------
// grid (32 qt, 64 b, 4 ch). Wave = 16 q x 1 head x <=256 keys (4 groups of 64), straight-line.
__global__ __launch_bounds__(256) void k_attn(
        const char* __restrict__ qf, const char* __restrict__ kf,
        const char* __restrict__ vf, const int* __restrict__ e,
        float* __restrict__ oacc, float* __restrict__ lacc) {
    __shared__ __align__(16) char Pb[18432];   // 4 waves x 2 bufs x (16 rows x 144B)
    int tid = threadIdx.x;
    int qt = blockIdx.x, b = blockIdx.y, ch = blockIdx.z;
    int kmax = e[b] + 1;
    int k0 = ch << 8;
    if (k0 >= kmax) return;
    int ng = min(4, (kmax - k0 + 63) >> 6);    // 1..4 live 64-key groups

    int wave = tid >> 6, lane = tid & 63, quad = lane >> 4, c = lane & 15;
    int h = wave & 1;
    int tile = (qt << 1) + (wave >> 1);
    int qbase = tile << 4;
    int bh = b * 2 + h;

    char* Pw = Pb + wave * 4608;
    // 256-key chunk spans kch8 groups 2*ch, 2*ch+1; group g's K pieces at +g*4096, V at +g*2048
    const char* kchunk = kf + ((size_t)((bh << 3) + (ch << 1)) << 13);
    const char* vchunk = vf + ((size_t)((bh << 3) + (ch << 1)) << 12);

    bf16x8 aQ = *(const bf16x8*)(qf + ((size_t)((bh << 6) + tile) << 10) + lane * 16);
    const f32x4 z4 = {0.0f, 0.0f, 0.0f, 0.0f};
    f32x4 accO = z4;
    float l_[4] = {0.0f, 0.0f, 0.0f, 0.0f};

#pragma unroll
    for (int g = 0; g < 4; g++) {
        if (g < ng) {
            const char* kg = kchunk + (size_t)g * 4096;
            const char* vg = vchunk + (size_t)g * 2048;
            bf16x8 bv0 = *(const bf16x8*)(vg + lane * 16);
            bf16x8 bv1 = *(const bf16x8*)(vg + 1024 + lane * 16);
            f32x4 st[4];
#pragma unroll
            for (int t = 0; t < 4; t++) {
                bf16x8 bkh = *(const bf16x8*)(kg + t * 1024 + lane * 16);
                st[t] = __builtin_amdgcn_mfma_f32_16x16x32_bf16(aQ, bkh, z4, 0, 0, 0);
            }
            if (k0 + g * 64 + 64 > kmax) {     // tail mask (last live group only)
#pragma unroll
                for (int t = 0; t < 4; t++) {
                    int key = k0 + g * 64 + 4 * c + t;
                    if (key >= kmax) st[t] = f32x4{-3e38f, -3e38f, -3e38f, -3e38f};
                }
            }
            float p[4][4];
#pragma unroll
            for (int t = 0; t < 4; t++)
#pragma unroll
                for (int r = 0; r < 4; r++) p[t][r] = exp2f(st[t][r]);
            char* Pg = Pw + (g & 1) * 2304;
#pragma unroll
            for (int r = 0; r < 4; r++) {
                l_[r] += (p[0][r] + p[1][r]) + (p[2][r] + p[3][r]);
                unsigned lo = pack_hi2(p[0][r], p[1][r]);
                unsigned hi = pack_hi2(p[2][r], p[3][r]);
                *(uint2*)(Pg + (quad * 4 + r) * 144 + c * 8) = uint2{lo, hi};
            }
            const char* Pra = Pg + c * 144 + quad * 16;
            bf16x8 aP0 = *(const bf16x8*)(Pra);
            bf16x8 aP1 = *(const bf16x8*)(Pra + 64);
            accO = __builtin_amdgcn_mfma_f32_16x16x32_bf16(aP0, bv0, accO, 0, 0, 0);
            accO = __builtin_amdgcn_mfma_f32_16x16x32_bf16(aP1, bv1, accO, 0, 0, 0);
        }
    }

#pragma unroll
    for (int d = 1; d < 16; d <<= 1) {
#pragma unroll
        for (int r = 0; r < 4; r++) l_[r] += __shfl_xor(l_[r], d, 16);
    }
#pragma unroll
    for (int r = 0; r < 4; r++) {
        int q = qbase + quad * 4 + r;
        atomicAdd(oacc + ((size_t)((bh << 10) + q)) * 16 + c, accO[r]);
        if (c == 0) atomicAdd(lacc + (bh << 10) + q, l_[r]);
    }
}

// ---------------- kernel 3: normalize + out = O @ W2^T + b2 ----------------
__global__ __launch_bounds__(256) void k_fc(
        const float* __restrict__ oacc, const float* __restrict__ lacc,
        const float* __restrict__ W2, const float* __restrict__ b2,
        float* __restrict__ out) {
    __shared__ float Ob[128 * 36];
    __shared__ float sW[VV * 36];
    __shared__ float sb[VV];
    int tid = threadIdx.x;
    for (int i = tid; i < VV * DD; i += 256) sW[(i >> 5) * 36 + (i & 31)] = W2[i];
    if (tid < VV) sb[tid] = b2[tid];

    int tl = tid >> 1, hh = tid & 1;
    int idx = blockIdx.x * 128 + tl;
    int b = idx >> 10, s = idx & 1023;
    size_t row = (size_t)((b * 2 + hh) << 10) + s;

    float inv = 1.0f / lacc[row];
    const float4* pr = (const float4*)(oacc + row * 16);
    float4 o0 = pr[0], o1 = pr[1], o2 = pr[2], o3 = pr[3];
    float* obr = Ob + tl * 36 + hh * DHH;
    obr[0]  = o0.x * inv; obr[1]  = o0.y * inv; obr[2]  = o0.z * inv; obr[3]  = o0.w * inv;
    obr[4]  = o1.x * inv; obr[5]  = o1.y * inv; obr[6]  = o1.z * inv; obr[7]  = o1.w * inv;
    obr[8]  = o2.x * inv; obr[9]  = o2.y * inv; obr[10] = o2.z * inv; obr[11] = o2.w * inv;
    obr[12] = o3.x * inv; obr[13] = o3.y * inv; obr[14] = o3.z * inv; obr[15] = o3.w * inv;
    __syncthreads();

    const float* orow = Ob + tl * 36;
    float ov[DD];
#pragma unroll
    for (int i = 0; i < DD; i += 4) {
        float4 t4 = *(const float4*)(orow + i);
        ov[i] = t4.x; ov[i + 1] = t4.y; ov[i + 2] = t4.z; ov[i + 3] = t4.w;
    }
    size_t obase = (size_t)idx * VV + hh * 14;
#pragma unroll
    for (int jj = 0; jj < 14; jj++) {
        int vv = hh * 14 + jj;
        float a = sb[vv];
#pragma unroll
        for (int d = 0; d < DD; d += 4) {
            float4 w4 = *(const float4*)(sW + vv * 36 + d);
            a += ov[d] * w4.x + ov[d + 1] * w4.y + ov[d + 2] * w4.z + ov[d + 3] * w4.w;
        }
        out[obase + jj] = a;
    }
}

extern "C" void kernel_launch(void* const* d_in, const int* in_sizes, int n_in,
                              void* d_out, int out_size, void* d_ws, size_t ws_size,
                              hipStream_t stream) {
    const int*   x    = (const int*)d_in[0];
    const float* mask = (const float*)d_in[1];
    const float* emb  = (const float*)d_in[2];
    const float* pe   = (const float*)d_in[3];
    const float* wq   = (const float*)d_in[4];
    const float* bq   = (const float*)d_in[5];
    const float* wk   = (const float*)d_in[6];
    const float* bk   = (const float*)d_in[7];
    const float* wv   = (const float*)d_in[8];
    const float* bv   = (const float*)d_in[9];
    const float* wo   = (const float*)d_in[10];
    const float* bo   = (const float*)d_in[11];
    const float* wfc  = (const float*)d_in[12];
    const float* bfc  = (const float*)d_in[13];
    float* out = (float*)d_out;

    char* ws = (char*)d_ws;
    int*   e  = (int*)ws;                                     // 256 B
    float* W2 = (float*)(ws + 256);
    float* b2 = (float*)(ws + 3840);
    char*  qf = ws + 4096;                                    // 8 MiB  [bh][tile][slot]
    char*  kf = qf + (size_t)8388608;                         // 8 MiB  [bh][kch8][piece][slot]
    char*  vf = kf + (size_t)8388608;                         // 4 MiB  [bh][kch8][piece][slot]
    float* oacc = (float*)(vf + (size_t)4194304);             // 8 MiB
    float* lacc = oacc + (size_t)BB * HH * SS * 16;           // 0.5 MiB

    hipLaunchKernelGGL(k_pre, dim3(1153), dim3(256), 0, stream,
                       x, mask, emb, pe, wq, bq, wk, bk, wv, bv, wo, bo, wfc, bfc,
                       e, W2, b2, qf, kf, vf, oacc);
    hipLaunchKernelGGL(k_attn, dim3(SS / 32, BB, NCH), dim3(256), 0, stream,
                       qf, kf, vf, e, oacc, lacc);
    hipLaunchKernelGGL(k_fc, dim3(BB * SS / 128), dim3(256), 0, stream,
                       oacc, lacc, W2, b2, out);
}

// Round 17
// 134.354 us; speedup vs baseline: 3.1726x; 1.0303x over previous
//
#include <hip/hip_runtime.h>
#include <math.h>

#define BB 64
#define SS 1024
#define DD 32
#define HH 2
#define DHH 16
#define VV 28
#define QSC 0.3606737602222409f   // 0.25 * log2(e)
#define NCH 2                     // 2 chunks of 512 keys

typedef __attribute__((ext_vector_type(8))) short bf16x8;
typedef __attribute__((ext_vector_type(4))) float f32x4;

__device__ __forceinline__ unsigned pack_hi2(float a, float b) {
    return __builtin_amdgcn_perm(__float_as_uint(b), __float_as_uint(a), 0x07060302u);
}
__device__ __forceinline__ float trunc_hi(float a) {
    return __uint_as_float(__float_as_uint(a) & 0xFFFF0000u);
}
__device__ __forceinline__ unsigned bf_rtne_u(float x) {
    unsigned u = __float_as_uint(x);
    return (u + 0x7FFFu + ((u >> 16) & 1u)) >> 16;
}
__device__ __forceinline__ unsigned pack_rtne2(float a, float b) {
    return bf_rtne_u(a) | (bf_rtne_u(b) << 16);
}
__device__ __forceinline__ bf16x8 as_bf16x8(uint4 u) {
    union { uint4 u; bf16x8 v; } cv; cv.u = u; return cv.v;
}

// Fragment-order layouts. Consumer lane l reads byte l*16.
//  qf[bh][tile(64)][slot(64)][16B]                 : Q A-frags (quads 0,1 hi / 2,3 lo) — exact hi/lo split
//  kf[bh][kch8(8)][piece(g*4+t)][slot][16B]        : K B-frags, RTNE bf16, [kh;kh] duplication baked in
//  vf[bh][kch8(8)][piece(g*2+sub)][slot][16B]      : V B-frags, RTNE bf16
// k_attn uses 512-key chunks = 4 consecutive kch8 groups; group g's pieces are contiguous.

// ---------------- kernel 1: MFMA QKV projection -> fragment order; e; W2; zero acc ----------
__global__ __launch_bounds__(256) void k_pre(
        const int* __restrict__ x, const float* __restrict__ mask,
        const float* __restrict__ emb, const float* __restrict__ pe,
        const float* __restrict__ wq, const float* __restrict__ bq,
        const float* __restrict__ wk, const float* __restrict__ bk,
        const float* __restrict__ wv, const float* __restrict__ bv,
        const float* __restrict__ wo, const float* __restrict__ bo,
        const float* __restrict__ wfc, const float* __restrict__ bfc,
        int* __restrict__ e, float* __restrict__ W2, float* __restrict__ b2,
        char* __restrict__ qf, char* __restrict__ kf, char* __restrict__ vf,
        float* __restrict__ zacc) {
    int bid = blockIdx.x;
    int tid = threadIdx.x;
    if (bid < 1024) {
        __shared__ __align__(16) char hbuf[10240];
        __shared__ __align__(16) float Cb[4][16 * 17];
        char* hHi = hbuf;
        char* hLo = hbuf + 5120;
        int wave = tid >> 6, lane = tid & 63;
        int c = lane & 15, kq = lane >> 4;
        {
            int tt = tid >> 2, q4 = tid & 3;
            int idx = bid * 64 + tt;
            int b = idx >> 10, s = idx & 1023;
            float nm = (mask[b * SS + (s >= 3 ? s - 3 : 0)] != 0.0f) ? 1.0f : 0.0f;
            int tok = x[idx];
            float h[8];
#pragma unroll
            for (int i = 0; i < 8; i++)
                h[i] = (emb[tok * DD + q4 * 8 + i] + pe[s * DD + q4 * 8 + i]) * nm;
            unsigned wh[4], wl[4];
#pragma unroll
            for (int wd = 0; wd < 4; wd++) {
                float a0 = h[2 * wd], a1 = h[2 * wd + 1];
                wh[wd] = pack_hi2(a0, a1);
                wl[wd] = pack_hi2(a0 - trunc_hi(a0), a1 - trunc_hi(a1));
            }
            *(uint4*)(hHi + tt * 80 + q4 * 16) = uint4{wh[0], wh[1], wh[2], wh[3]};
            *(uint4*)(hLo + tt * 80 + q4 * 16) = uint4{wl[0], wl[1], wl[2], wl[3]};
        }
        __syncthreads();
        bf16x8 aHh, aHl;
        {
            int off = (wave * 16 + c) * 80 + kq * 16;
            aHh = *(const bf16x8*)(hHi + off);
            aHl = *(const bf16x8*)(hLo + off);
        }
        int blk_b = bid >> 4;
        int s_w = ((bid * 64) & 1023) + wave * 16;   // wave's 16 tokens start
        const f32x4 z4 = {0.0f, 0.0f, 0.0f, 0.0f};
#pragma unroll
        for (int M = 0; M < 3; M++) {
            const float* W    = M == 0 ? wq : (M == 1 ? wk : wv);
            const float* bias = M == 0 ? bq : (M == 1 ? bk : bv);
            bf16x8 Bh[2], Bl[2];
            float bv_[2];
#pragma unroll
            for (int nt = 0; nt < 2; nt++) {
                const float* wrow = W + (nt * 16 + c) * DD + kq * 8;
                float4 wa = ((const float4*)wrow)[0];
                float4 wb = ((const float4*)wrow)[1];
                float f[8] = {wa.x, wa.y, wa.z, wa.w, wb.x, wb.y, wb.z, wb.w};
                unsigned uh[4], ul[4];
#pragma unroll
                for (int wd = 0; wd < 4; wd++) {
                    float a0 = f[2 * wd], a1 = f[2 * wd + 1];
                    uh[wd] = pack_hi2(a0, a1);
                    ul[wd] = pack_hi2(a0 - trunc_hi(a0), a1 - trunc_hi(a1));
                }
                Bh[nt] = as_bf16x8(uint4{uh[0], uh[1], uh[2], uh[3]});
                Bl[nt] = as_bf16x8(uint4{ul[0], ul[1], ul[2], ul[3]});
                bv_[nt] = bias[nt * 16 + c];
            }
#pragma unroll
            for (int nt = 0; nt < 2; nt++) {
                f32x4 acc = __builtin_amdgcn_mfma_f32_16x16x32_bf16(aHh, Bh[nt], z4, 0, 0, 0);
                acc = __builtin_amdgcn_mfma_f32_16x16x32_bf16(aHl, Bh[nt], acc, 0, 0, 0);
                acc = __builtin_amdgcn_mfma_f32_16x16x32_bf16(aHh, Bl[nt], acc, 0, 0, 0);
#pragma unroll
                for (int r = 0; r < 4; r++) {
                    float val = acc[r] + bv_[nt];
                    if (M == 0) val *= QSC;
                    Cb[wave][(kq * 4 + r) * 17 + c] = val;
                }
                int bh = blk_b * 2 + nt;
                if (M == 0) {
                    // Q: exact hi/lo split (quads 0,1 hi; 2,3 lo), truncation split (exact sum)
                    int tile = s_w >> 4;
                    int qd = lane >> 4, cc = lane & 15;
                    float f[8];
#pragma unroll
                    for (int j = 0; j < 8; j++) f[j] = Cb[wave][cc * 17 + (qd & 1) * 8 + j];
                    unsigned u[4];
                    if (qd < 2) {
#pragma unroll
                        for (int wd = 0; wd < 4; wd++) u[wd] = pack_hi2(f[2 * wd], f[2 * wd + 1]);
                    } else {
#pragma unroll
                        for (int wd = 0; wd < 4; wd++) {
                            float a0 = f[2 * wd] - trunc_hi(f[2 * wd]);
                            float a1 = f[2 * wd + 1] - trunc_hi(f[2 * wd + 1]);
                            u[wd] = pack_hi2(a0, a1);
                        }
                    }
                    *(uint4*)(qf + ((size_t)((bh << 6) + tile) << 10) + lane * 16)
                        = uint4{u[0], u[1], u[2], u[3]};
                } else if (M == 1) {
                    // K: single RTNE plane, [kh;kh] duplication via qd 0-3
                    int cl = lane & 3, qd = (lane >> 2) & 3, t = lane >> 4;
                    int ch = s_w >> 7, g = (s_w >> 6) & 1, c0 = (s_w & 63) >> 2;
                    int keyl = 4 * cl + t;
                    float f[8];
#pragma unroll
                    for (int j = 0; j < 8; j++) f[j] = Cb[wave][keyl * 17 + (qd & 1) * 8 + j];
                    unsigned uh[4];
#pragma unroll
                    for (int wd = 0; wd < 4; wd++) uh[wd] = pack_rtne2(f[2 * wd], f[2 * wd + 1]);
                    char* base = kf + ((size_t)((bh << 3) + ch) << 13)
                               + ((g << 2) + t) * 1024 + qd * 256 + (c0 + cl) * 16;
                    *(uint4*)(base) = uint4{uh[0], uh[1], uh[2], uh[3]};
                } else if (lane < 32) {
                    // V: RTNE bf16
                    int ch = s_w >> 7, g = (s_w >> 6) & 1, sub = (s_w >> 5) & 1;
                    int qs = (s_w & 31) >> 3;
                    int qrel = lane >> 4, dh = lane & 15;
                    unsigned u[4];
#pragma unroll
                    for (int wd = 0; wd < 4; wd++) {
                        float f0 = Cb[wave][(qrel * 8 + 2 * wd) * 17 + dh];
                        float f1 = Cb[wave][(qrel * 8 + 2 * wd + 1) * 17 + dh];
                        u[wd] = pack_rtne2(f0, f1);
                    }
                    *(uint4*)(vf + ((size_t)((bh << 3) + ch) << 12)
                              + (g * 2 + sub) * 1024 + (qs + qrel) * 256 + dh * 16)
                        = uint4{u[0], u[1], u[2], u[3]};
                }
            }
        }
    } else if (bid < 1088) {
        int b = bid - 1024;
        int lm = -1;
        for (int s = tid; s < SS; s += 256)
            if (mask[b * SS + s] != 0.0f) lm = s;
        __shared__ int red[256];
        red[tid] = lm;
        __syncthreads();
        for (int off = 128; off > 0; off >>= 1) {
            if (tid < off) red[tid] = max(red[tid], red[tid + off]);
            __syncthreads();
        }
        if (tid == 0) {
            int last = red[0];
            int ee = last;
            if (last < SS - 1) ee = min(last + 3, SS - 1);
            e[b] = ee;
        }
    } else if (bid == 1088) {
        for (int t2 = tid; t2 < VV * DD + VV; t2 += 256) {
            if (t2 < VV * DD) {
                int vv = t2 / DD, i = t2 % DD;
                float a = 0.0f;
                for (int j = 0; j < DD; j++) a += wfc[vv * DD + j] * wo[j * DD + i];
                W2[t2] = a;
            } else {
                int vv = t2 - VV * DD;
                float a = bfc[vv];
                for (int j = 0; j < DD; j++) a += wfc[vv * DD + j] * bo[j];
                b2[vv] = a;
            }
        }
    } else {
        // zero oacc + lacc = 557056 float4 (contiguous)
        float4* z = (float4*)zacc;
        const float4 z4 = {0.0f, 0.0f, 0.0f, 0.0f};
        for (int i = (bid - 1089) * 256 + tid; i < 557056; i += 64 * 256) z[i] = z4;
    }
}

// ---------------- kernel 2: max-free MFMA attention, 512-key chunks, single-plane K ---------
// grid (32 qt, 64 b, 2 ch). Wave = 16 q x 1 head x <=512 keys (8 groups of 64), straight-line.
__global__ __launch_bounds__(256) void k_attn(
        const char* __restrict__ qf, const char* __restrict__ kf,
        const char* __restrict__ vf, const int* __restrict__ e,
        float* __restrict__ oacc, float* __restrict__ lacc) {
    __shared__ __align__(16) char Pb[18432];   // 4 waves x 2 bufs x (16 rows x 144B)
    int tid = threadIdx.x;
    int qt = blockIdx.x, b = blockIdx.y, ch = blockIdx.z;
    int kmax = e[b] + 1;
    int k0 = ch << 9;
    if (k0 >= kmax) return;
    int ng = min(8, (kmax - k0 + 63) >> 6);    // 1..8 live 64-key groups

    int wave = tid >> 6, lane = tid & 63, quad = lane >> 4, c = lane & 15;
    int h = wave & 1;
    int tile = (qt << 1) + (wave >> 1);
    int qbase = tile << 4;
    int bh = b * 2 + h;

    char* Pw = Pb + wave * 4608;
    // 512-key chunk spans kch8 groups 4*ch..4*ch+3; group g's K pieces at +g*4096, V at +g*2048
    const char* kchunk = kf + ((size_t)((bh << 3) + (ch << 2)) << 13);
    const char* vchunk = vf + ((size_t)((bh << 3) + (ch << 2)) << 12);

    bf16x8 aQ = *(const bf16x8*)(qf + ((size_t)((bh << 6) + tile) << 10) + lane * 16);
    const f32x4 z4 = {0.0f, 0.0f, 0.0f, 0.0f};
    f32x4 accO = z4;
    float l_[4] = {0.0f, 0.0f, 0.0f, 0.0f};

#pragma unroll
    for (int g = 0; g < 8; g++) {
        if (g < ng) {
            const char* kg = kchunk + (size_t)g * 4096;
            const char* vg = vchunk + (size_t)g * 2048;
            bf16x8 bv0 = *(const bf16x8*)(vg + lane * 16);
            bf16x8 bv1 = *(const bf16x8*)(vg + 1024 + lane * 16);
            f32x4 st[4];
#pragma unroll
            for (int t = 0; t < 4; t++) {
                bf16x8 bkh = *(const bf16x8*)(kg + t * 1024 + lane * 16);
                st[t] = __builtin_amdgcn_mfma_f32_16x16x32_bf16(aQ, bkh, z4, 0, 0, 0);
            }
            if (k0 + g * 64 + 64 > kmax) {     // tail mask (last live group only)
#pragma unroll
                for (int t = 0; t < 4; t++) {
                    int key = k0 + g * 64 + 4 * c + t;
                    if (key >= kmax) st[t] = f32x4{-3e38f, -3e38f, -3e38f, -3e38f};
                }
            }
            float p[4][4];
#pragma unroll
            for (int t = 0; t < 4; t++)
#pragma unroll
                for (int r = 0; r < 4; r++) p[t][r] = exp2f(st[t][r]);
            char* Pg = Pw + (g & 1) * 2304;
#pragma unroll
            for (int r = 0; r < 4; r++) {
                l_[r] += (p[0][r] + p[1][r]) + (p[2][r] + p[3][r]);
                unsigned lo = pack_hi2(p[0][r], p[1][r]);
                unsigned hi = pack_hi2(p[2][r], p[3][r]);
                *(uint2*)(Pg + (quad * 4 + r) * 144 + c * 8) = uint2{lo, hi};
            }
            const char* Pra = Pg + c * 144 + quad * 16;
            bf16x8 aP0 = *(const bf16x8*)(Pra);
            bf16x8 aP1 = *(const bf16x8*)(Pra + 64);
            accO = __builtin_amdgcn_mfma_f32_16x16x32_bf16(aP0, bv0, accO, 0, 0, 0);
            accO = __builtin_amdgcn_mfma_f32_16x16x32_bf16(aP1, bv1, accO, 0, 0, 0);
        }
    }

#pragma unroll
    for (int d = 1; d < 16; d <<= 1) {
#pragma unroll
        for (int r = 0; r < 4; r++) l_[r] += __shfl_xor(l_[r], d, 16);
    }
#pragma unroll
    for (int r = 0; r < 4; r++) {
        int q = qbase + quad * 4 + r;
        atomicAdd(oacc + ((size_t)((bh << 10) + q)) * 16 + c, accO[r]);
        if (c == 0) atomicAdd(lacc + (bh << 10) + q, l_[r]);
    }
}

// ---------------- kernel 3: normalize + out = O @ W2^T + b2 ----------------
__global__ __launch_bounds__(256) void k_fc(
        const float* __restrict__ oacc, const float* __restrict__ lacc,
        const float* __restrict__ W2, const float* __restrict__ b2,
        float* __restrict__ out) {
    __shared__ float Ob[128 * 36];
    __shared__ float sW[VV * 36];
    __shared__ float sb[VV];
    int tid = threadIdx.x;
    for (int i = tid; i < VV * DD; i += 256) sW[(i >> 5) * 36 + (i & 31)] = W2[i];
    if (tid < VV) sb[tid] = b2[tid];

    int tl = tid >> 1, hh = tid & 1;
    int idx = blockIdx.x * 128 + tl;
    int b = idx >> 10, s = idx & 1023;
    size_t row = (size_t)((b * 2 + hh) << 10) + s;

    float inv = 1.0f / lacc[row];
    const float4* pr = (const float4*)(oacc + row * 16);
    float4 o0 = pr[0], o1 = pr[1], o2 = pr[2], o3 = pr[3];
    float* obr = Ob + tl * 36 + hh * DHH;
    obr[0]  = o0.x * inv; obr[1]  = o0.y * inv; obr[2]  = o0.z * inv; obr[3]  = o0.w * inv;
    obr[4]  = o1.x * inv; obr[5]  = o1.y * inv; obr[6]  = o1.z * inv; obr[7]  = o1.w * inv;
    obr[8]  = o2.x * inv; obr[9]  = o2.y * inv; obr[10] = o2.z * inv; obr[11] = o2.w * inv;
    obr[12] = o3.x * inv; obr[13] = o3.y * inv; obr[14] = o3.z * inv; obr[15] = o3.w * inv;
    __syncthreads();

    const float* orow = Ob + tl * 36;
    float ov[DD];
#pragma unroll
    for (int i = 0; i < DD; i += 4) {
        float4 t4 = *(const float4*)(orow + i);
        ov[i] = t4.x; ov[i + 1] = t4.y; ov[i + 2] = t4.z; ov[i + 3] = t4.w;
    }
    size_t obase = (size_t)idx * VV + hh * 14;
#pragma unroll
    for (int jj = 0; jj < 14; jj++) {
        int vv = hh * 14 + jj;
        float a = sb[vv];
#pragma unroll
        for (int d = 0; d < DD; d += 4) {
            float4 w4 = *(const float4*)(sW + vv * 36 + d);
            a += ov[d] * w4.x + ov[d + 1] * w4.y + ov[d + 2] * w4.z + ov[d + 3] * w4.w;
        }
        out[obase + jj] = a;
    }
}

extern "C" void kernel_launch(void* const* d_in, const int* in_sizes, int n_in,
                              void* d_out, int out_size, void* d_ws, size_t ws_size,
                              hipStream_t stream) {
    const int*   x    = (const int*)d_in[0];
    const float* mask = (const float*)d_in[1];
    const float* emb  = (const float*)d_in[2];
    const float* pe   = (const float*)d_in[3];
    const float* wq   = (const float*)d_in[4];
    const float* bq   = (const float*)d_in[5];
    const float* wk   = (const float*)d_in[6];
    const float* bk   = (const float*)d_in[7];
    const float* wv   = (const float*)d_in[8];
    const float* bv   = (const float*)d_in[9];
    const float* wo   = (const float*)d_in[10];
    const float* bo   = (const float*)d_in[11];
    const float* wfc  = (const float*)d_in[12];
    const float* bfc  = (const float*)d_in[13];
    float* out = (float*)d_out;

    char* ws = (char*)d_ws;
    int*   e  = (int*)ws;                                     // 256 B
    float* W2 = (float*)(ws + 256);
    float* b2 = (float*)(ws + 3840);
    char*  qf = ws + 4096;                                    // 8 MiB  [bh][tile][slot]
    char*  kf = qf + (size_t)8388608;                         // 8 MiB  [bh][kch8][piece][slot]
    char*  vf = kf + (size_t)8388608;                         // 4 MiB  [bh][kch8][piece][slot]
    float* oacc = (float*)(vf + (size_t)4194304);             // 8 MiB
    float* lacc = oacc + (size_t)BB * HH * SS * 16;           // 0.5 MiB

    hipLaunchKernelGGL(k_pre, dim3(1153), dim3(256), 0, stream,
                       x, mask, emb, pe, wq, bq, wk, bk, wv, bv, wo, bo, wfc, bfc,
                       e, W2, b2, qf, kf, vf, oacc);
    hipLaunchKernelGGL(k_attn, dim3(SS / 32, BB, NCH), dim3(256), 0, stream,
                       qf, kf, vf, e, oacc, lacc);
    hipLaunchKernelGGL(k_fc, dim3(BB * SS / 128), dim3(256), 0, stream,
                       oacc, lacc, W2, b2, out);
}